// Round 15
// baseline (392.216 us; speedup 1.0000x reference)
//
#include <hip/hip_runtime.h>

// ---------------- constants ----------------
#define LOG_DELTA (-5.2983174f)   // ln(0.005)
#define LOG50     (3.9120230054f) // ln(50)

typedef __attribute__((ext_vector_type(8))) short short8v;
typedef __attribute__((ext_vector_type(4))) float f32x4;

// ws layout (float offsets)
constexpr size_t OFF_C1G1  = 0;                       // c1u u32 [12][32][50]
constexpr size_t OFF_KLDP  = 19200;                   // kld partials [600]
constexpr size_t OFF_ACCS  = 38400;                   // [16]
constexpr size_t OFF_C0G   = 38416;                   // bzg bf16 [12][50][7000]
constexpr size_t OFF_BETA  = OFF_C0G  + 4200000;      // [600][7000] logits
constexpr size_t OFF_ALPHAT= OFF_BETA + 4200000;      // inp_f32 [384][400]
constexpr size_t OFF_INP   = OFF_ALPHAT + 180000;     // inp_bf ushort[384][416]
constexpr size_t OFF_X0    = OFF_INP  + 153600;       // [384][1600]
constexpr size_t OFF_OUT0  = OFF_X0   + 614400;       // hs0 [384][400]
constexpr size_t OFF_X1    = OFF_OUT0 + 153600;       // cst1|albf|r2bf region
constexpr size_t OFF_OUT1  = OFF_X1   + 614400;       // hs1 [384][400]
constexpr size_t OFF_CST   = OFF_OUT1 + 153600;       // cst0 [32][400]
constexpr size_t OFF_MUH   = OFF_CST  + 12800;        // [384][100]
constexpr size_t OFF_THETA = OFF_MUH  + 38400;        // [12][32][50]
constexpr size_t OFF_LTH   = OFF_THETA+ 19200;        // bsum0|bsum1|mlb|rs
constexpr size_t OFF_MUW4  = OFF_LTH  + 19200;        // [50][400]
constexpr size_t OFF_LSW4  = OFF_MUW4 + 20000;        // [50][400]
constexpr size_t OFF_RS    = OFF_LTH  + 3300;         // rowsum [2][600]
// overlay in bzg region (dead before pass1): block-packed LSTM weights
constexpr size_t OFF_W0P   = OFF_C0G;                 // f32 [200][400][8]
constexpr size_t OFF_W1P   = OFF_C0G + 640000;        // f32 [200][400][8]
constexpr size_t OFF_WI1P  = OFF_C0G + 1280000;       // f32 [200][400][8]
constexpr size_t OFF_NBBF  = OFF_C0G + 1920000;       // ushort[384][7040]
constexpr size_t OFF_R1BF  = OFF_C0G + 3271680;       // ushort[5000][320]
// overlay in beta region (dead before beta GEMMs):
constexpr size_t OFF_QWBF  = OFF_BETA;                // ushort[400][7040]
constexpr size_t OFF_W0BF  = OFF_BETA + 1408000;      // ushort[1600][416]
// overlay in X1 region (X1 eliminated):
constexpr size_t OFF_CST1  = OFF_X1;                  // f32 [32][400]
constexpr size_t OFF_ALBF  = OFF_X1 + 12800;          // ushort[600][320]
constexpr size_t OFF_R2BF  = OFF_X1 + 108800;         // ushort[2000][320]

// ---------------- helpers ----------------
__device__ __forceinline__ float wsum64(float x){
  #pragma unroll
  for (int o = 32; o; o >>= 1) x += __shfl_down(x, o);
  return x;
}
__device__ __forceinline__ float u01(unsigned int x){
  x ^= x >> 16; x *= 0x7feb352dU;
  x ^= x >> 15; x *= 0x846ca68bU;
  x ^= x >> 16;
  return ((float)x + 0.5f) * (1.0f/4294967296.0f);
}
__device__ __forceinline__ unsigned short f2bf(float x){
  unsigned int u = __float_as_uint(x);
  u += 0x7FFFu + ((u >> 16) & 1u);
  return (unsigned short)(u >> 16);
}
__device__ __forceinline__ float bf2f(unsigned short u){
  return __uint_as_float(((unsigned int)u) << 16);
}
__device__ __forceinline__ ushort4 f4bf(float4 v){
  ushort4 r;
  r.x = f2bf(v.x); r.y = f2bf(v.y); r.z = f2bf(v.z); r.w = f2bf(v.w);
  return r;
}

// ---------------- fused prep (vectorized) + kld_alpha (blocks >= 2048) ------
__global__ void prep_misc(float* __restrict__ ws,
    const float* __restrict__ muW, const float* __restrict__ lsW,
    const float* __restrict__ qmu, const float* __restrict__ qls,
    const float* __restrict__ bi0, const float* __restrict__ bh0,
    const float* __restrict__ bi1, const float* __restrict__ bh1,
    const float* __restrict__ mb,  const float* __restrict__ lb,
    const float* __restrict__ qb,
    const float* __restrict__ whh0, const float* __restrict__ whh1,
    const float* __restrict__ wih1,
    const float* __restrict__ nbows, const float* __restrict__ qmap_w,
    const float* __restrict__ wih0,
    const float* __restrict__ rho1w, const float* __restrict__ rho2w)
{
  const int tid = threadIdx.x;
  if (blockIdx.x >= 2048){
    // ---- kld_alpha: one block per (t,k), partial to kldp[bid2] ----
    float* kldp = ws + OFF_KLDP;
    const int bid2 = blockIdx.x - 2048;
    const int t = bid2 / 50, k = bid2 % 50;
    if (tid < 64){
      const size_t base  = ((size_t)k*12 + t)*300;
      const size_t pbase = ((size_t)k*12 + (t-1))*300;
      const float dd  = (t > 0) ? (expf(LOG_DELTA) + 1e-6f) : (1.f + 1e-6f);
      const float pls = (t > 0) ? LOG_DELTA : 0.f;
      float s = 0.f;
      for (int r = tid; r < 300; r += 64){
        float qm = qmu[base + r], ql = qls[base + r];
        float pm = (t > 0) ? qmu[pbase + r] : 0.f;
        float d = qm - pm;
        s += (expf(ql) + d*d)/dd - 1.f + pls - ql;
      }
      s = wsum64(s);
      if (tid == 0) kldp[bid2] = 0.5f * s / 50.f;
    }
    return;
  }

  float* zbase = ws + OFF_C1G1;          // zero c1u [0,19200) + accs
  float* muW4  = ws + OFF_MUW4;
  float* lsW4  = ws + OFF_LSW4;
  unsigned short* albf = (unsigned short*)(ws + OFF_ALBF);
  float* bsum0 = ws + OFF_LTH;
  float* bsum1 = ws + OFF_LTH + 1600;
  float* mlb   = ws + OFF_LTH + 3200;
  float* rs    = ws + OFF_RS;
  unsigned int* inbz = (unsigned int*)(ws + OFF_INP);
  float* inpf  = ws + OFF_ALPHAT;
  float* w0P   = ws + OFF_W0P;
  float* w1P   = ws + OFF_W1P;
  float* wi1P  = ws + OFF_WI1P;
  unsigned short* nbbf = (unsigned short*)(ws + OFF_NBBF);
  unsigned short* qwbf = (unsigned short*)(ws + OFF_QWBF);
  unsigned short* w0bf = (unsigned short*)(ws + OFF_W0BF);
  unsigned short* r1bf = (unsigned short*)(ws + OFF_R1BF);
  unsigned short* r2bf = (unsigned short*)(ws + OFF_R2BF);
  const float4 z4 = {0.f, 0.f, 0.f, 0.f};
  // zero ranges: c1u [0,19200) + accs [38400,38416): handled via two unit sets
  // unit map (x4 elems each):
  //  [0,4800)        zero c1u (19200 f32)
  //  [4800,4804)     zero accs (16 f32)
  //  [4804,9804)     muW4
  //  [9804,14804)    lsW4
  //  [14804,62804)   albf
  //  [62804,63204)   bsum0
  //  [63204,63604)   bsum1
  //  [63604,63629)   mlb
  //  [63629,63929)   rs
  //  [63929,83897)   inbz
  //  [83897,563897)  w packs
  //  [563897,1239737) nbbf
  //  [1239737,1943737) qwbf
  //  [1943737,2110137) w0bf
  //  [2110137,2510137) r1bf
  //  [2510137,2670137) r2bf
  //  [2670137,2708537) inpf
  for (long long un = (long long)blockIdx.x*256 + tid; un < 2708537LL;
       un += 2048LL*256){
    if (un < 4800){
      int j = (int)un * 4;
      *(float4*)&zbase[j] = z4;
    }
    else if (un < 4804){
      int j = (int)(un - 4800) * 4;
      *(float4*)&ws[OFF_ACCS + j] = z4;
    }
    else if (un < 9804){
      int j = (int)(un - 4804) * 4;
      int k = j / 400, c = j % 400;
      const float* s = &muW[k*450 + c];
      float4 v = {s[0], s[1], s[2], s[3]};
      *(float4*)&muW4[j] = v;
    }
    else if (un < 14804){
      int j = (int)(un - 9804) * 4;
      int k = j / 400, c = j % 400;
      const float* s = &lsW[k*450 + c];
      float4 v = {s[0], s[1], s[2], s[3]};
      *(float4*)&lsW4[j] = v;
    }
    else if (un < 62804){
      int j = (int)(un - 14804) * 4;
      int m = j / 320, r = j % 320;
      int t = m / 50, k = m % 50;
      ushort4 o = {0,0,0,0};
      if (r < 300) o = f4bf(*(const float4*)&qmu[((size_t)k*12 + t)*300 + r]);
      *(ushort4*)&albf[j] = o;
    }
    else if (un < 63204){
      int j = (int)(un - 62804) * 4;
      float4 a = *(const float4*)&bi0[j], b = *(const float4*)&bh0[j];
      float4 v = {a.x+b.x, a.y+b.y, a.z+b.z, a.w+b.w};
      *(float4*)&bsum0[j] = v;
    }
    else if (un < 63604){
      int j = (int)(un - 63204) * 4;
      float4 a = *(const float4*)&bi1[j], b = *(const float4*)&bh1[j];
      float4 v = {a.x+b.x, a.y+b.y, a.z+b.z, a.w+b.w};
      *(float4*)&bsum1[j] = v;
    }
    else if (un < 63629){
      int j = (int)(un - 63604) * 4;
      #pragma unroll
      for (int q = 0; q < 4; ++q){
        int jj = j + q;
        mlb[jj] = (jj < 50) ? mb[jj] : lb[jj-50];
      }
    }
    else if (un < 63929){
      int j = (int)(un - 63629) * 4;
      *(float4*)&rs[j] = z4;
    }
    else if (un < 83897){
      int j = (int)(un - 63929) * 4;
      *(uint4*)&inbz[j] = make_uint4(0u,0u,0u,0u);
    }
    else if (un < 563897){
      long long rel = un - 83897;
      int half = (int)(rel / 160000);
      int j = (int)(rel % 160000) * 4;
      int ub = j / 3200, rem = j % 3200;
      int r = rem / 8, c = rem % 8;
      int ul = c >> 2;
      int u = ub*2 + ul;
      const float* src = (half == 0) ? whh0 : (half == 1) ? whh1 : wih1;
      float* dst = (half == 0) ? w0P : (half == 1) ? w1P : wi1P;
      float4 v = { src[((size_t)(0*400 + u))*400 + r],
                   src[((size_t)(1*400 + u))*400 + r],
                   src[((size_t)(2*400 + u))*400 + r],
                   src[((size_t)(3*400 + u))*400 + r] };
      *(float4*)&dst[j] = v;
    }
    else if (un < 1239737){
      int j = (int)(un - 563897) * 4;
      int row = j / 7040, v = j % 7040;
      ushort4 o = {0,0,0,0};
      if (v < 7000) o = f4bf(*(const float4*)&nbows[(size_t)row*7000 + v]);
      *(ushort4*)&nbbf[j] = o;
    }
    else if (un < 1943737){
      int j = (int)(un - 1239737) * 4;
      int row = j / 7040, v = j % 7040;
      ushort4 o = {0,0,0,0};
      if (v < 7000) o = f4bf(*(const float4*)&qmap_w[(size_t)row*7000 + v]);
      *(ushort4*)&qwbf[j] = o;
    }
    else if (un < 2110137){
      int j = (int)(un - 1943737) * 4;
      int row = j / 416, r = j % 416;
      ushort4 o = {0,0,0,0};
      if (r < 400) o = f4bf(*(const float4*)&wih0[(size_t)row*400 + r]);
      *(ushort4*)&w0bf[j] = o;
    }
    else if (un < 2510137){
      int j = (int)(un - 2110137) * 4;
      int row = j / 320, r = j % 320;
      ushort4 o = {0,0,0,0};
      if (r < 300) o = f4bf(*(const float4*)&rho1w[(size_t)row*300 + r]);
      *(ushort4*)&r1bf[j] = o;
    }
    else if (un < 2670137){
      int j = (int)(un - 2510137) * 4;
      int row = j / 320, r = j % 320;
      ushort4 o = {0,0,0,0};
      if (r < 300) o = f4bf(*(const float4*)&rho2w[(size_t)row*300 + r]);
      *(ushort4*)&r2bf[j] = o;
    }
    else {
      int j = (int)(un - 2670137) * 4;
      int c = j % 400;
      *(float4*)&inpf[j] = *(const float4*)&qb[c];
    }
  }
}

// ---------------- MFMA bf16 GEMM ----------------
__global__ __launch_bounds__(256) void gemm_bf16(
    const unsigned short* __restrict__ A, int lda,
    const unsigned short* __restrict__ B, int ldb,
    float* __restrict__ Cf, unsigned short* __restrict__ Cbf,
    float* __restrict__ Cacc, int ldc,
    int M, int N, int Kp, int kchunk,
    const float* __restrict__ bias, float* __restrict__ rowsum)
{
  __shared__ unsigned short As[64][40];
  __shared__ unsigned short Bs[64][40];
  __shared__ float sexp[64];
  const int tid = threadIdx.x;
  const int m0 = blockIdx.y * 64, n0 = blockIdx.x * 64;
  const int kbeg = blockIdx.z * kchunk;
  const int kend = min(Kp, kbeg + kchunk);
  const int wave = tid >> 6, lane = tid & 63;
  const int wm = (wave >> 1) * 32, wn = (wave & 1) * 32;
  const int ra = tid >> 2, ck = (tid & 3) << 3;
  const int fr = lane & 15, fo = (lane >> 4) << 3;
  if (rowsum && tid < 64) sexp[tid] = 0.f;

  f32x4 acc00 = {0.f,0.f,0.f,0.f}, acc01 = {0.f,0.f,0.f,0.f};
  f32x4 acc10 = {0.f,0.f,0.f,0.f}, acc11 = {0.f,0.f,0.f,0.f};
  int4 pa, pb;
  {
    int rA = m0 + ra, rB = n0 + ra;
    pa = (rA < M) ? *(const int4*)&A[(size_t)rA*lda + kbeg + ck] : make_int4(0,0,0,0);
    pb = (rB < N) ? *(const int4*)&B[(size_t)rB*ldb + kbeg + ck] : make_int4(0,0,0,0);
  }
  for (int k0 = kbeg; k0 < kend; k0 += 32){
    *(int4*)&As[ra][ck] = pa;
    *(int4*)&Bs[ra][ck] = pb;
    __syncthreads();
    if (k0 + 32 < kend){
      int rA = m0 + ra, rB = n0 + ra;
      pa = (rA < M) ? *(const int4*)&A[(size_t)rA*lda + k0 + 32 + ck] : make_int4(0,0,0,0);
      pb = (rB < N) ? *(const int4*)&B[(size_t)rB*ldb + k0 + 32 + ck] : make_int4(0,0,0,0);
    }
    short8v a0 = *(const short8v*)&As[wm      + fr][fo];
    short8v a1 = *(const short8v*)&As[wm + 16 + fr][fo];
    short8v b0 = *(const short8v*)&Bs[wn      + fr][fo];
    short8v b1 = *(const short8v*)&Bs[wn + 16 + fr][fo];
    acc00 = __builtin_amdgcn_mfma_f32_16x16x32_bf16(a0, b0, acc00, 0, 0, 0);
    acc01 = __builtin_amdgcn_mfma_f32_16x16x32_bf16(a0, b1, acc01, 0, 0, 0);
    acc10 = __builtin_amdgcn_mfma_f32_16x16x32_bf16(a1, b0, acc10, 0, 0, 0);
    acc11 = __builtin_amdgcn_mfma_f32_16x16x32_bf16(a1, b1, acc11, 0, 0, 0);
    __syncthreads();
  }
  const int rbase = (lane >> 4) << 2;
  auto epi = [&](f32x4 ac0, f32x4 ac1, int mi){
    #pragma unroll
    for (int reg = 0; reg < 4; ++reg){
      const int lr = wm + mi*16 + rbase + reg;
      const int gr = m0 + lr;
      float ex = 0.f;
      {
        int gc = n0 + wn + fr;
        if (gr < M && gc < N){
          if (Cacc) atomicAdd(&Cacc[(size_t)gr*ldc + gc], ac0[reg]);
          else {
            float val = ac0[reg] + (bias ? bias[gc] : 0.f);
            if (Cbf) Cbf[(size_t)gr*ldc + gc] = f2bf(val);
            else     Cf [(size_t)gr*ldc + gc] = val;
            if (rowsum) ex += __expf(val);
          }
        }
      }
      {
        int gc = n0 + wn + 16 + fr;
        if (gr < M && gc < N){
          if (Cacc) atomicAdd(&Cacc[(size_t)gr*ldc + gc], ac1[reg]);
          else {
            float val = ac1[reg] + (bias ? bias[gc] : 0.f);
            if (Cbf) Cbf[(size_t)gr*ldc + gc] = f2bf(val);
            else     Cf [(size_t)gr*ldc + gc] = val;
            if (rowsum) ex += __expf(val);
          }
        }
      }
      if (rowsum){
        ex += __shfl_xor(ex, 1); ex += __shfl_xor(ex, 2);
        ex += __shfl_xor(ex, 4); ex += __shfl_xor(ex, 8);
        if (fr == 0 && gr < M) atomicAdd(&sexp[lr], ex);
      }
    }
  };
  epi(acc00, acc01, 0);
  epi(acc10, acc11, 1);
  if (rowsum){
    __syncthreads();
    if (tid < 64 && m0 + tid < M) atomicAdd(&rowsum[m0 + tid], sexp[tid]);
  }
}

// ---------------- convert inp_f32 -> bf16 (vectorized) ----------------
__global__ void cvt_inp(const float* __restrict__ inpf, unsigned short* __restrict__ inpbf){
  int un = blockIdx.x*blockDim.x + threadIdx.x;
  if (un < 38400){
    int j = un * 4;
    int r = j / 400, c = j % 400;
    ushort4 o = f4bf(*(const float4*)&inpf[j]);
    *(ushort4*)&inpbf[r*416 + c] = o;
  }
}

// ---------------- f32 GEMM (kept for tiny muH2) ----------------
__device__ __forceinline__ float4 g4(const float* __restrict__ base, int row, int nrows,
                                     int ld, int k, int kend){
  float4 v; v.x = v.y = v.z = v.w = 0.f;
  if (row < nrows){
    const float* q = base + (size_t)row*ld + k;
    if (k + 3 < kend) v = *(const float4*)q;
  }
  return v;
}
__global__ __launch_bounds__(256) void gemm_f32(
    const float* __restrict__ A, int lda,
    const float* __restrict__ B, int ldb,
    float* __restrict__ C, int ldc,
    int M, int N, int K,
    const float* __restrict__ bias)
{
  __shared__ __align__(16) float As[16][68];
  __shared__ __align__(16) float Bs[16][68];
  const int tid = threadIdx.x;
  const int m0 = blockIdx.y * 64, n0 = blockIdx.x * 64;
  const int lm  = tid >> 2;
  const int lkq = (tid & 3) << 2;
  const int ty = tid >> 4, tx = tid & 15;
  float acc[4][4];
  #pragma unroll
  for (int i=0;i<4;++i)
    #pragma unroll
    for (int j=0;j<4;++j) acc[i][j] = 0.f;
  for (int k0 = 0; k0 < K; k0 += 16){
    float4 av = g4(A, m0+lm, M, lda, k0+lkq, K);
    float4 bv = g4(B, n0+lm, N, ldb, k0+lkq, K);
    As[lkq+0][lm]=av.x; As[lkq+1][lm]=av.y; As[lkq+2][lm]=av.z; As[lkq+3][lm]=av.w;
    Bs[lkq+0][lm]=bv.x; Bs[lkq+1][lm]=bv.y; Bs[lkq+2][lm]=bv.z; Bs[lkq+3][lm]=bv.w;
    __syncthreads();
    #pragma unroll
    for (int kk = 0; kk < 16; ++kk){
      const float4 a = *(const float4*)&As[kk][ty<<2];
      const float4 b = *(const float4*)&Bs[kk][tx<<2];
      float ar[4] = {a.x,a.y,a.z,a.w};
      float br[4] = {b.x,b.y,b.z,b.w};
      #pragma unroll
      for (int i=0;i<4;++i)
        #pragma unroll
        for (int j=0;j<4;++j) acc[i][j] = fmaf(ar[i], br[j], acc[i][j]);
    }
    __syncthreads();
  }
  const int om = m0 + (ty<<2), on = n0 + (tx<<2);
  #pragma unroll
  for (int i=0;i<4;++i)
    #pragma unroll
    for (int j=0;j<4;++j)
      if (om+i < M && on+j < N)
        C[(size_t)(om+i)*ldc + (on+j)] = acc[i][j] + (bias ? bias[on+j] : 0.f);
}

// ---------------- pipelined LSTM v3: bf16 h staging (LDS 42.4KB) ----------------
__global__ __launch_bounds__(256) void lstm_pipe(
    const float* __restrict__ X0,    const float* __restrict__ w0P,
    const float* __restrict__ wi1P,  const float* __restrict__ w1P,
    const float* __restrict__ bsum1,
    float* __restrict__ hs0, float* __restrict__ hs1,
    float* __restrict__ cst0, float* __restrict__ cst1, int step)
{
  __shared__ __align__(16) ushort4 hqb[100*32];  // bf16 h [rq][b]  25.6KB
  __shared__ __align__(16) float4 wq4[400*2];    // [r][ul]  12.8KB
  __shared__ __align__(16) float4 red4[4][32][2];
  const int tid = threadIdx.x;
  const int rh = tid >> 6;
  const int b  = (tid & 63) >> 1;
  const int ul = tid & 1;
  const int rq0 = rh * 25;

  if (blockIdx.x < 200){
    const int t = step;
    if (t >= 12) return;
    const int ub = blockIdx.x;
    const int U0 = ub * 2;
    if (t > 0){
      for (int i = tid; i < 3200; i += 256){
        int bb = i & 31, rq = i >> 5;
        hqb[rq*32 + bb] = f4bf(*(const float4*)&hs0[((size_t)(bb*12 + (t-1)))*400 + rq*4]);
      }
      for (int i = tid; i < 800; i += 256)
        wq4[i] = *(const float4*)&w0P[(size_t)ub*3200 + i*4];
      __syncthreads();
      float4 acc = {0.f,0.f,0.f,0.f};
      #pragma unroll 5
      for (int rq = rq0; rq < rq0 + 25; ++rq){
        ushort4 h4 = hqb[rq*32 + b];
        float hr[4] = {bf2f(h4.x), bf2f(h4.y), bf2f(h4.z), bf2f(h4.w)};
        #pragma unroll
        for (int dr = 0; dr < 4; ++dr){
          float4 w4 = wq4[(rq*4 + dr)*2 + ul];
          acc.x = fmaf(hr[dr], w4.x, acc.x);
          acc.y = fmaf(hr[dr], w4.y, acc.y);
          acc.z = fmaf(hr[dr], w4.z, acc.z);
          acc.w = fmaf(hr[dr], w4.w, acc.w);
        }
      }
      red4[rh][b][ul] = acc;
    }
    __syncthreads();
    if (tid < 64){
      const int bb = tid >> 1, uu = U0 + (tid & 1);
      float4 a = {0.f,0.f,0.f,0.f};
      if (t > 0){
        #pragma unroll
        for (int w = 0; w < 4; ++w){
          float4 r = red4[w][bb][tid & 1];
          a.x += r.x; a.y += r.y; a.z += r.z; a.w += r.w;
        }
      }
      const size_t xrow = ((size_t)bb*12 + t)*1600;
      float gi = a.x + X0[xrow          + uu];
      float gf = a.y + X0[xrow +  400   + uu];
      float gg = a.z + X0[xrow +  800   + uu];
      float go = a.w + X0[xrow + 1200   + uu];
      float ii = 1.f/(1.f + expf(-gi));
      float ff = 1.f/(1.f + expf(-gf));
      float tg = tanhf(gg);
      float oo = 1.f/(1.f + expf(-go));
      float c = (t == 0) ? 0.f : cst0[bb*400 + uu];
      c = ff*c + ii*tg;
      cst0[bb*400 + uu] = c;
      hs0[((size_t)bb*12 + t)*400 + uu] = oo * tanhf(c);
    }
  } else {
    const int t = step - 1;
    if (t < 0) return;
    const int ub = blockIdx.x - 200;
    const int U0 = ub * 2;
    float4 acc = {0.f,0.f,0.f,0.f};
    for (int i = tid; i < 3200; i += 256){
      int bb = i & 31, rq = i >> 5;
      hqb[rq*32 + bb] = f4bf(*(const float4*)&hs0[((size_t)(bb*12 + t))*400 + rq*4]);
    }
    for (int i = tid; i < 800; i += 256)
      wq4[i] = *(const float4*)&wi1P[(size_t)ub*3200 + i*4];
    __syncthreads();
    {
      #pragma unroll 5
      for (int rq = rq0; rq < rq0 + 25; ++rq){
        ushort4 h4 = hqb[rq*32 + b];
        float hr[4] = {bf2f(h4.x), bf2f(h4.y), bf2f(h4.z), bf2f(h4.w)};
        #pragma unroll
        for (int dr = 0; dr < 4; ++dr){
          float4 w4 = wq4[(rq*4 + dr)*2 + ul];
          acc.x = fmaf(hr[dr], w4.x, acc.x);
          acc.y = fmaf(hr[dr], w4.y, acc.y);
          acc.z = fmaf(hr[dr], w4.z, acc.z);
          acc.w = fmaf(hr[dr], w4.w, acc.w);
        }
      }
    }
    __syncthreads();
    if (t > 0){
      for (int i = tid; i < 3200; i += 256){
        int bb = i & 31, rq = i >> 5;
        hqb[rq*32 + bb] = f4bf(*(const float4*)&hs1[((size_t)(bb*12 + (t-1)))*400 + rq*4]);
      }
      for (int i = tid; i < 800; i += 256)
        wq4[i] = *(const float4*)&w1P[(size_t)ub*3200 + i*4];
    }
    __syncthreads();
    if (t > 0){
      #pragma unroll 5
      for (int rq = rq0; rq < rq0 + 25; ++rq){
        ushort4 h4 = hqb[rq*32 + b];
        float hr[4] = {bf2f(h4.x), bf2f(h4.y), bf2f(h4.z), bf2f(h4.w)};
        #pragma unroll
        for (int dr = 0; dr < 4; ++dr){
          float4 w4 = wq4[(rq*4 + dr)*2 + ul];
          acc.x = fmaf(hr[dr], w4.x, acc.x);
          acc.y = fmaf(hr[dr], w4.y, acc.y);
          acc.z = fmaf(hr[dr], w4.z, acc.z);
          acc.w = fmaf(hr[dr], w4.w, acc.w);
        }
      }
    }
    red4[rh][b][ul] = acc;
    __syncthreads();
    if (tid < 64){
      const int bb = tid >> 1, uu = U0 + (tid & 1);
      float4 a = {0.f,0.f,0.f,0.f};
      #pragma unroll
      for (int w = 0; w < 4; ++w){
        float4 r = red4[w][bb][tid & 1];
        a.x += r.x; a.y += r.y; a.z += r.z; a.w += r.w;
      }
      float gi = a.x + bsum1[        uu];
      float gf = a.y + bsum1[ 400 + uu];
      float gg = a.z + bsum1[ 800 + uu];
      float go = a.w + bsum1[1200 + uu];
      float ii = 1.f/(1.f + expf(-gi));
      float ff = 1.f/(1.f + expf(-gf));
      float tg = tanhf(gg);
      float oo = 1.f/(1.f + expf(-go));
      float c = (t == 0) ? 0.f : cst1[bb*400 + uu];
      c = ff*c + ii*tg;
      cst1[bb*400 + uu] = c;
      hs1[((size_t)bb*12 + t)*400 + uu] = oo * tanhf(c);
    }
  }
}

// ---------------- theta head: one block per batch row b ----------------
__global__ __launch_bounds__(64) void theta_par(
    const float* __restrict__ muH2,
    const float* __restrict__ muW, const float* __restrict__ lsW,
    float* __restrict__ theta, float* __restrict__ accs)
{
  __shared__ float wm[50][51], wl[50][51];
  __shared__ float zs[12][50];
  const int tid = threadIdx.x;
  const int b = blockIdx.x;
  for (int i = tid; i < 2500; i += 64){
    int k = i / 50, j = i % 50;
    wm[k][j] = muW[k*450 + 400 + j];
    wl[k][j] = lsW[k*450 + 400 + j];
  }
  __syncthreads();
  const float dd = expf(LOG_DELTA) + 1e-6f;
  float kacc = 0.f;
  for (int t = 0; t < 12; ++t){
    float kpart = 0.f;
    if (tid < 50){
      int k = tid;
      float m = muH2[((size_t)b*12 + t)*100 + k];
      float l = muH2[((size_t)b*12 + t)*100 + 50 + k];
      float zp = 0.f;
      if (t > 0){
        zp = zs[t-1][k];
        float sm = 0.f, sl = 0.f;
        #pragma unroll 5
        for (int j = 0; j < 50; ++j){
          float z = zs[t-1][j];
          sm = fmaf(z, wm[k][j], sm);
          sl = fmaf(z, wl[k][j], sl);
        }
        m += sm; l += sl;
      }
      zs[t][k] = m;
      float denom = (t > 0) ? dd : (1.f + 1e-6f);
      float pls = (t > 0) ? LOG_DELTA : 0.f;
      float d = m - zp;
      kpart = (expf(l) + d*d)/denom - 1.f + pls - l;
    }
    kpart = wsum64(kpart);
    if (tid == 0) kacc += 0.5f * kpart / 32.f;
    __syncthreads();
  }
  if (tid < 12){
    int t = tid;
    float m = -3.0e38f;
    for (int k = 0; k < 50; ++k) m = fmaxf(m, zs[t][k]);
    float S = 0.f;
    for (int k = 0; k < 50; ++k) S += expf(zs[t][k] - m);
    float inv = 1.f/S;
    for (int k = 0; k < 50; ++k)
      theta[((size_t)t*32 + b)*50 + k] = expf(zs[t][k] - m) * inv;
  }
  if (tid == 0) atomicAdd(&accs[6], kacc);
}

// ---------------- pass1 v9: bf16 bzg output ----------------
__global__ __launch_bounds__(256) void pass1(
    const float* __restrict__ blog, const float* __restrict__ rs,
    const float* __restrict__ theta,
    unsigned short* __restrict__ bzg,
    unsigned int* __restrict__ c1u,
    float* __restrict__ accs)
{
  const int t = blockIdx.y;
  const int v0 = blockIdx.x * 64;
  __shared__ float th[32][50];
  __shared__ __align__(16) float be[50][64];
  __shared__ unsigned int c0p[64][13];
  __shared__ unsigned int c1p[2][32][25];
  __shared__ float rlog[2][50];
  __shared__ float kred[4];
  const int tid = threadIdx.x;

  if (tid < 100){
    int p = tid / 50, k = tid % 50;
    rlog[p][k] = __logf(rs[p*600 + t*50 + k]);
  }
  float lg[13];
  #pragma unroll
  for (int j = 0; j < 13; ++j){
    int i = tid + j*256;
    lg[j] = -40.f;
    if (i < 3200){
      int k = i >> 6, vl = i & 63, v = v0 + vl;
      if (v < 7000) lg[j] = blog[((size_t)t*50 + k)*7000 + v];
    }
  }
  #pragma unroll
  for (int j = 0; j < 7; ++j){
    int i = tid + j*256;
    if (i < 1600) th[i/50][i%50] = theta[(size_t)t*1600 + i];
  }
  for (int i = tid; i < 832; i += 256) ((unsigned int*)c0p)[i] = 0u;
  #pragma unroll
  for (int j = 0; j < 7; ++j){
    int i = tid + j*256;
    if (i < 1600) ((unsigned int*)c1p)[i] = 0u;
  }
  if (tid < 4) kred[tid] = 0.f;
  __syncthreads();
  #pragma unroll
  for (int j = 0; j < 13; ++j){
    int i = tid + j*256;
    if (i < 3200){
      int k = i >> 6, vl = i & 63, v = v0 + vl;
      int p = (v >= 5000);
      be[k][vl] = __expf(lg[j] - rlog[p][k]);
    }
  }
  __syncthreads();

  const int b = tid >> 3, sub = tid & 7;
  int off[8];
  #pragma unroll
  for (int i = 0; i < 8; ++i) off[i] = ((i >> 2) ? 32 : 0) + sub*4 + (i & 3);

  float sx[8], mx[8];
  #pragma unroll
  for (int i = 0; i < 8; ++i){ sx[i] = 0.f; mx[i] = 0.f; }
  for (int k = 0; k < 50; ++k){
    float tk = th[b][k];
    float4 q0 = *(const float4*)&be[k][sub*4];
    float4 q1 = *(const float4*)&be[k][32 + sub*4];
    float bv[8] = {q0.x,q0.y,q0.z,q0.w,q1.x,q1.y,q1.z,q1.w};
    #pragma unroll
    for (int i = 0; i < 8; ++i){
      float x = tk * bv[i];
      sx[i] += x;
      mx[i] = fmaxf(mx[i], x);
    }
  }
  float inv[8], lS1[8], bnd[8];
  #pragma unroll
  for (int i = 0; i < 8; ++i){
    inv[i] = 1.f / (50.f + sx[i]);
    lS1[i] = LOG50 + sx[i] * 0.02f;
    bnd[i] = (1.f + mx[i]) * inv[i];
  }

  int ks[8]; float xs[8];
  unsigned fmask = 0;
  const int sbase = (t*32 + b)*7000 + v0;
  #pragma unroll
  for (int i = 0; i < 8; ++i){
    ks[i] = 0; xs[i] = 0.f;
    if (v0 + off[i] >= 7000) fmask |= 1u << i;
  }
  int round = 0;
  while (true){
    const unsigned roff = (unsigned)round * 0x9E3779B9u;
    #pragma unroll
    for (int i = 0; i < 8; ++i){
      if (!((fmask >> i) & 1u)){
        const unsigned bse = (unsigned)(sbase + off[i]) * 2u;
        float u1 = u01(bse + roff);
        float u2 = u01(bse + 1u + roff);
        int kp = min((int)(u1 * 50.f), 49);
        float x  = th[b][kp] * be[kp][off[i]];
        float pi = (1.f + x) * inv[i];
        float y  = pi - bnd[i];
        float ap = 1.f + y + 0.5f*y*y;
        if (u2 <= ap || round >= 7){
          ks[i] = kp; xs[i] = x; fmask |= 1u << i;
        }
      }
    }
    ++round;
    if (__all(fmask == 255u)) break;
  }

  float kA1 = 0.f, kB1 = 0.f, kA2 = 0.f, kB2 = 0.f;
  #pragma unroll
  for (int i = 0; i < 8; ++i){
    const int vl = off[i], v = v0 + vl;
    if (v < 7000){
      float pis  = (1.f + xs[i]) * inv[i];
      float lpis = xs[i] - lS1[i];
      float lt   = __logf(th[b][ks[i]]);
      if (v >= 5000){ kA2 += lt; kB2 += pis*lpis; }
      else          { kA1 += lt; kB1 += pis*lpis; }
      atomicAdd(&c0p[vl][ks[i] >> 2], 1u << (8*(ks[i] & 3)));
      atomicAdd(&c1p[(v >= 5000) ? 1 : 0][b][ks[i] >> 1],
                (ks[i] & 1) ? 65536u : 1u);
    }
  }
  kA1 = wsum64(kA1); kB1 = wsum64(kB1); kA2 = wsum64(kA2); kB2 = wsum64(kB2);
  if ((tid & 63) == 0){
    atomicAdd(&kred[0], kA1); atomicAdd(&kred[1], kB1);
    atomicAdd(&kred[2], kA2); atomicAdd(&kred[3], kB2);
  }
  __syncthreads();
  #pragma unroll
  for (int j = 0; j < 13; ++j){
    int i = tid + j*256;
    if (i < 3200){
      int k = i >> 6, vl = i & 63, v = v0 + vl;
      if (v < 7000){
        float cnt = (float)((c0p[vl][k >> 2] >> (8*(k & 3))) & 0xFFu);
        bzg[(size_t)t*350000 + (size_t)k*7000 + v] = f2bf(be[k][vl] * cnt * (1.f/32.f));
      }
    }
  }
  for (int i = tid; i < 1600; i += 256){
    int b2 = i / 50, k2 = i % 50;
    unsigned w1 = c1p[0][b2][k2 >> 1];
    unsigned w2 = c1p[1][b2][k2 >> 1];
    unsigned cnt1 = (k2 & 1) ? (w1 >> 16) : (w1 & 0xFFFFu);
    unsigned cnt2 = (k2 & 1) ? (w2 >> 16) : (w2 & 0xFFFFu);
    unsigned comb = cnt1 | (cnt2 << 16);
    if (comb) atomicAdd(&c1u[(size_t)t*1600 + i], comb);
  }
  if (tid < 4) atomicAdd(&accs[tid], kred[tid]);
}

// ---------------- pass2: log-likelihood (bf16 bzg) ----------------
__global__ __launch_bounds__(256) void pass2(
    const unsigned short* __restrict__ bzg, const float* __restrict__ theta,
    const unsigned int* __restrict__ c1u,
    const float* __restrict__ bows, float* __restrict__ accs)
{
  const int t = blockIdx.y, v0 = blockIdx.x * 64;
  __shared__ float tz[2][32][50];
  __shared__ __align__(16) float bzs[50][64];
  __shared__ float sr[2];
  const int tid = threadIdx.x;
  if (tid < 2) sr[tid] = 0.f;
  for (int i = tid; i < 1600; i += 256){
    int b = i / 50, k = i % 50;
    float th_ = theta[(size_t)t*1600 + i];
    unsigned cw = c1u[(size_t)t*1600 + i];
    tz[0][b][k] = th_ * (float)(cw & 0xFFFFu) * (1.f/5000.f);
    tz[1][b][k] = th_ * (float)(cw >> 16)     * (1.f/2000.f);
  }
  for (int i = tid; i < 3200; i += 256){
    int k = i >> 6, vl = i & 63, v = v0 + vl;
    bzs[k][vl] = (v < 7000) ? bf2f(bzg[(size_t)t*350000 + (size_t)k*7000 + v]) : 0.f;
  }
  __syncthreads();

  const int b = tid >> 3, sub = tid & 7;
  int off[8];
  #pragma unroll
  for (int i = 0; i < 8; ++i) off[i] = ((i >> 2) ? 32 : 0) + sub*4 + (i & 3);
  int part[8];
  #pragma unroll
  for (int i = 0; i < 8; ++i) part[i] = (v0 + off[i] >= 5000);
  float dot[8];
  #pragma unroll
  for (int i = 0; i < 8; ++i) dot[i] = 0.f;
  for (int k = 0; k < 50; ++k){
    float t0 = tz[0][b][k], t1 = tz[1][b][k];
    float4 q0 = *(const float4*)&bzs[k][sub*4];
    float4 q1 = *(const float4*)&bzs[k][32 + sub*4];
    float bv[8] = {q0.x,q0.y,q0.z,q0.w,q1.x,q1.y,q1.z,q1.w};
    #pragma unroll
    for (int i = 0; i < 8; ++i)
      dot[i] = fmaf(part[i] ? t1 : t0, bv[i], dot[i]);
  }
  float w8[8];
  const size_t brow = ((size_t)b*12 + t)*7000;
  if (v0 + 63 < 7000){
    float4 wa = *(const float4*)&bows[brow + v0 + sub*4];
    float4 wb = *(const float4*)&bows[brow + v0 + 32 + sub*4];
    w8[0]=wa.x; w8[1]=wa.y; w8[2]=wa.z; w8[3]=wa.w;
    w8[4]=wb.x; w8[5]=wb.y; w8[6]=wb.z; w8[7]=wb.w;
  } else {
    #pragma unroll
    for (int i = 0; i < 8; ++i)
      w8[i] = (v0 + off[i] < 7000) ? bows[brow + v0 + off[i]] : 0.f;
  }
  float s1 = 0.f, s2 = 0.f;
  #pragma unroll
  for (int i = 0; i < 8; ++i){
    const int v = v0 + off[i];
    if (v < 7000){
      const float l = __logf(dot[i]) * w8[i];
      if (part[i]) s2 += l; else s1 += l;
    }
  }
  s1 = wsum64(s1); s2 = wsum64(s2);
  if ((tid & 63) == 0){ atomicAdd(&sr[0], s1); atomicAdd(&sr[1], s2); }
  __syncthreads();
  if (tid < 2) atomicAdd(&accs[4 + tid], sr[tid]);
}

// ---------------- finalize (sums kld partials too) ----------------
__global__ void finalize_k(const float* __restrict__ accs,
                           const float* __restrict__ kldp,
                           float* __restrict__ out){
  const int tid = threadIdx.x;
  float s = 0.f;
  for (int i = tid; i < 600; i += 64) s += kldp[i];
  s = wsum64(s);
  if (tid == 0){
    out[0] = -(accs[4] + accs[5]) * (1.f/32.f);
    out[1] = accs[6];
    out[2] = -accs[0]/(32.f*5000.f) - accs[1]/32.f;
    out[3] = -accs[2]/(32.f*2000.f) - accs[3]/32.f;
    out[4] = s;
  }
}

// ---------------- host launcher ----------------
extern "C" void kernel_launch(void* const* d_in, const int* in_sizes, int n_in,
                              void* d_out, int out_size, void* d_ws, size_t ws_size,
                              hipStream_t stream)
{
  const float* bows   = (const float*)d_in[0];
  const float* nbows  = (const float*)d_in[1];
  const float* qmap_w = (const float*)d_in[2];
  const float* qmap_b = (const float*)d_in[3];
  const float* wih0   = (const float*)d_in[4];
  const float* whh0   = (const float*)d_in[5];
  const float* bih0   = (const float*)d_in[6];
  const float* bhh0   = (const float*)d_in[7];
  const float* wih1   = (const float*)d_in[8];
  const float* whh1   = (const float*)d_in[9];
  const float* bih1   = (const float*)d_in[10];
  const float* bhh1   = (const float*)d_in[11];
  const float* muW    = (const float*)d_in[12];
  const float* muB    = (const float*)d_in[13];
  const float* lsW    = (const float*)d_in[14];
  const float* lsB    = (const float*)d_in[15];
  const float* qmu    = (const float*)d_in[16];
  const float* qlsa   = (const float*)d_in[17];
  const float* rho1w  = (const float*)d_in[18];
  const float* rho1b  = (const float*)d_in[19];
  const float* rho2w  = (const float*)d_in[20];
  const float* rho2b  = (const float*)d_in[21];

  float* ws  = (float*)d_ws;
  float* out = (float*)d_out;

  unsigned int* c1u = (unsigned int*)(ws + OFF_C1G1);
  float* kldp  = ws + OFF_KLDP;
  float* accs  = ws + OFF_ACCS;
  unsigned short* bzg = (unsigned short*)(ws + OFF_C0G);
  float* beta  = ws + OFF_BETA;
  float* inpf  = ws + OFF_ALPHAT;
  float* X0    = ws + OFF_X0;
  float* hs0   = ws + OFF_OUT0;
  float* hs1   = ws + OFF_OUT1;
  float* cst0  = ws + OFF_CST;
  float* cst1  = ws + OFF_CST1;
  float* muH2  = ws + OFF_MUH;
  float* theta = ws + OFF_THETA;
  float* muW4  = ws + OFF_MUW4;
  float* bsum0 = ws + OFF_LTH;
  float* bsum1 = ws + OFF_LTH + 1600;
  float* mlb   = ws + OFF_LTH + 3200;
  float* rs    = ws + OFF_RS;
  unsigned short* nbbf  = (unsigned short*)(ws + OFF_NBBF);
  unsigned short* qwbf  = (unsigned short*)(ws + OFF_QWBF);
  unsigned short* inpbf = (unsigned short*)(ws + OFF_INP);
  unsigned short* w0bf  = (unsigned short*)(ws + OFF_W0BF);
  unsigned short* albf  = (unsigned short*)(ws + OFF_ALBF);
  unsigned short* r1bf  = (unsigned short*)(ws + OFF_R1BF);
  unsigned short* r2bf  = (unsigned short*)(ws + OFF_R2BF);
  float* w0P  = ws + OFF_W0P;
  float* w1P  = ws + OFF_W1P;
  float* wi1P = ws + OFF_WI1P;

  // prep (blocks 0..2047) + kld_alpha (blocks 2048..2647)
  prep_misc<<<2648, 256, 0, stream>>>(ws, muW, lsW, qmu, qlsa, bih0, bhh0,
                                      bih1, bhh1, muB, lsB, qmap_b,
                                      whh0, whh1, wih1,
                                      nbows, qmap_w, wih0, rho1w, rho2w);

  // inp_f32 += nbows_bf @ qmap_w_bf^T  (split-K x10; bias pre-init'd in prep)
  gemm_bf16<<<dim3(7,6,10), 256, 0, stream>>>(nbbf, 7040, qwbf, 7040,
                                              nullptr, nullptr, inpf, 400,
                                              384, 400, 7040, 704, nullptr, nullptr);
  cvt_inp<<<150, 256, 0, stream>>>(inpf, inpbf);

  // X0 = inp_bf @ wih0^T + (bih0+bhh0)     M=384 N=1600 Kp=416
  gemm_bf16<<<dim3(25,6,1), 256, 0, stream>>>(inpbf, 416, w0bf, 416,
                                              X0, nullptr, nullptr, 1600,
                                              384, 1600, 416, 416, bsum0, nullptr);
  // pipelined double-layer LSTM: 13 launches
  for (int i = 0; i < 13; ++i)
    lstm_pipe<<<400, 256, 0, stream>>>(X0, w0P, wi1P, w1P, bsum1,
                                       hs0, hs1, cst0, cst1, i);

  // muH2 = hs1 @ [muW4;lsW4]^T + [muB;lsB]
  gemm_f32<<<dim3(2,6), 256, 0, stream>>>(hs1, 400, muW4, 400, muH2, 100,
                                          384, 100, 400, mlb);
  theta_par<<<32, 64, 0, stream>>>(muH2, muW, lsW, theta, accs);

  // beta logits via MFMA + fused row sum(exp)
  gemm_bf16<<<dim3(79,10,1), 256, 0, stream>>>(albf, 320, r1bf, 320,
                                               beta, nullptr, nullptr, 7000,
                                               600, 5000, 320, 320, rho1b, rs);
  gemm_bf16<<<dim3(32,10,1), 256, 0, stream>>>(albf, 320, r2bf, 320,
                                               beta + 5000, nullptr, nullptr, 7000,
                                               600, 2000, 320, 320, rho2b, rs + 600);

  pass1<<<dim3(110,12), 256, 0, stream>>>(beta, rs, theta, bzg, c1u, accs);
  pass2<<<dim3(110,12), 256, 0, stream>>>(bzg, theta, c1u, bows, accs);

  finalize_k<<<1, 64, 0, stream>>>(accs, kldp, out);
}

// Round 16
// 387.524 us; speedup vs baseline: 1.0121x; 1.0121x over previous
//
#include <hip/hip_runtime.h>

// ---------------- constants ----------------
#define LOG_DELTA (-5.2983174f)   // ln(0.005)
#define LOG50     (3.9120230054f) // ln(50)

typedef __attribute__((ext_vector_type(8))) short short8v;
typedef __attribute__((ext_vector_type(4))) float f32x4;

// ws layout (float offsets)
constexpr size_t OFF_C1G1  = 0;                       // c1u u32 [12][32][50]
constexpr size_t OFF_KLDP  = 19200;                   // kld partials [600]
constexpr size_t OFF_ACCS  = 38400;                   // [16]
constexpr size_t OFF_C0G   = 38416;                   // bzg bf16 [12][50][7000]
constexpr size_t OFF_BETA  = OFF_C0G  + 4200000;      // [600][7000] logits
constexpr size_t OFF_ALPHAT= OFF_BETA + 4200000;      // inp_f32 [384][400]
constexpr size_t OFF_INP   = OFF_ALPHAT + 180000;     // (unused pad)
constexpr size_t OFF_X0    = OFF_INP  + 153600;       // [384][1600]
constexpr size_t OFF_OUT0  = OFF_X0   + 614400;       // hs0 [384][400]
constexpr size_t OFF_X1    = OFF_OUT0 + 153600;       // cst1|albf|r2bf region
constexpr size_t OFF_OUT1  = OFF_X1   + 614400;       // hs1 [384][400]
constexpr size_t OFF_CST   = OFF_OUT1 + 153600;       // cst0 [32][400]
constexpr size_t OFF_MUH   = OFF_CST  + 12800;        // (unused)
constexpr size_t OFF_THETA = OFF_MUH  + 38400;        // [12][32][50]
constexpr size_t OFF_LTH   = OFF_THETA+ 19200;        // bsum0|bsum1|mlb|rs
constexpr size_t OFF_MUW4  = OFF_LTH  + 19200;        // [100][400] (mu|ls)
constexpr size_t OFF_LSW4  = OFF_MUW4 + 20000;
constexpr size_t OFF_RS    = OFF_LTH  + 3300;         // rowsum [2][600]
// overlay in bzg region (dead before pass1): block-packed LSTM weights
constexpr size_t OFF_W0P   = OFF_C0G;                 // f32 [200][400][8]
constexpr size_t OFF_W1P   = OFF_C0G + 640000;
constexpr size_t OFF_WI1P  = OFF_C0G + 1280000;
constexpr size_t OFF_NBBF  = OFF_C0G + 1920000;       // ushort[384][7040]
constexpr size_t OFF_R1BF  = OFF_C0G + 3271680;       // ushort[5000][320]
// overlay in beta region (dead before beta GEMMs):
constexpr size_t OFF_QWBF  = OFF_BETA;                // ushort[400][7040]
constexpr size_t OFF_W0BF  = OFF_BETA + 1408000;      // ushort[1600][416]
// overlay in X1 region:
constexpr size_t OFF_CST1  = OFF_X1;                  // f32 [32][400]
constexpr size_t OFF_ALBF  = OFF_X1 + 12800;          // ushort[600][320]
constexpr size_t OFF_R2BF  = OFF_X1 + 108800;         // ushort[2000][320]

// ---------------- helpers ----------------
__device__ __forceinline__ float wsum64(float x){
  #pragma unroll
  for (int o = 32; o; o >>= 1) x += __shfl_down(x, o);
  return x;
}
__device__ __forceinline__ float u01(unsigned int x){
  x ^= x >> 16; x *= 0x7feb352dU;
  x ^= x >> 15; x *= 0x846ca68bU;
  x ^= x >> 16;
  return ((float)x + 0.5f) * (1.0f/4294967296.0f);
}
__device__ __forceinline__ unsigned short f2bf(float x){
  unsigned int u = __float_as_uint(x);
  u += 0x7FFFu + ((u >> 16) & 1u);
  return (unsigned short)(u >> 16);
}
__device__ __forceinline__ float bf2f(unsigned short u){
  return __uint_as_float(((unsigned int)u) << 16);
}
__device__ __forceinline__ ushort4 f4bf(float4 v){
  ushort4 r;
  r.x = f2bf(v.x); r.y = f2bf(v.y); r.z = f2bf(v.z); r.w = f2bf(v.w);
  return r;
}

// ---------------- fused prep (vectorized) + kld_alpha (blocks >= 2048) ------
__global__ void prep_misc(float* __restrict__ ws,
    const float* __restrict__ muW, const float* __restrict__ lsW,
    const float* __restrict__ qmu, const float* __restrict__ qls,
    const float* __restrict__ bi0, const float* __restrict__ bh0,
    const float* __restrict__ bi1, const float* __restrict__ bh1,
    const float* __restrict__ mb,  const float* __restrict__ lb,
    const float* __restrict__ qb,
    const float* __restrict__ whh0, const float* __restrict__ whh1,
    const float* __restrict__ wih1,
    const float* __restrict__ nbows, const float* __restrict__ qmap_w,
    const float* __restrict__ wih0,
    const float* __restrict__ rho1w, const float* __restrict__ rho2w)
{
  const int tid = threadIdx.x;
  if (blockIdx.x >= 2048){
    float* kldp = ws + OFF_KLDP;
    const int bid2 = blockIdx.x - 2048;
    const int t = bid2 / 50, k = bid2 % 50;
    if (tid < 64){
      const size_t base  = ((size_t)k*12 + t)*300;
      const size_t pbase = ((size_t)k*12 + (t-1))*300;
      const float dd  = (t > 0) ? (expf(LOG_DELTA) + 1e-6f) : (1.f + 1e-6f);
      const float pls = (t > 0) ? LOG_DELTA : 0.f;
      float s = 0.f;
      for (int r = tid; r < 300; r += 64){
        float qm = qmu[base + r], ql = qls[base + r];
        float pm = (t > 0) ? qmu[pbase + r] : 0.f;
        float d = qm - pm;
        s += (expf(ql) + d*d)/dd - 1.f + pls - ql;
      }
      s = wsum64(s);
      if (tid == 0) kldp[bid2] = 0.5f * s / 50.f;
    }
    return;
  }

  float* zbase = ws + OFF_C1G1;
  float* muW4  = ws + OFF_MUW4;
  float* lsW4  = ws + OFF_LSW4;
  unsigned short* albf = (unsigned short*)(ws + OFF_ALBF);
  float* bsum0 = ws + OFF_LTH;
  float* bsum1 = ws + OFF_LTH + 1600;
  float* mlb   = ws + OFF_LTH + 3200;
  float* rs    = ws + OFF_RS;
  float* inpf  = ws + OFF_ALPHAT;
  float* w0P   = ws + OFF_W0P;
  float* w1P   = ws + OFF_W1P;
  float* wi1P  = ws + OFF_WI1P;
  unsigned short* nbbf = (unsigned short*)(ws + OFF_NBBF);
  unsigned short* qwbf = (unsigned short*)(ws + OFF_QWBF);
  unsigned short* w0bf = (unsigned short*)(ws + OFF_W0BF);
  unsigned short* r1bf = (unsigned short*)(ws + OFF_R1BF);
  unsigned short* r2bf = (unsigned short*)(ws + OFF_R2BF);
  const float4 z4 = {0.f, 0.f, 0.f, 0.f};
  // unit map (x4):
  //  [0,4800) zero c1u | [4800,4804) zero accs | [4804,9804) muW4 | [9804,14804) lsW4
  //  [14804,62804) albf | [62804,63204) bsum0 | [63204,63604) bsum1 | [63604,63629) mlb
  //  [63629,63929) rs | [63929,563929) w packs | [563929,1239769) nbbf
  //  [1239769,1943769) qwbf | [1943769,2110169) w0bf | [2110169,2510169) r1bf
  //  [2510169,2670169) r2bf | [2670169,2708569) inpf
  for (long long un = (long long)blockIdx.x*256 + tid; un < 2708569LL;
       un += 2048LL*256){
    if (un < 4800){
      int j = (int)un * 4;
      *(float4*)&zbase[j] = z4;
    }
    else if (un < 4804){
      int j = (int)(un - 4800) * 4;
      *(float4*)&ws[OFF_ACCS + j] = z4;
    }
    else if (un < 9804){
      int j = (int)(un - 4804) * 4;
      int k = j / 400, c = j % 400;
      const float* s = &muW[k*450 + c];
      float4 v = {s[0], s[1], s[2], s[3]};
      *(float4*)&muW4[j] = v;
    }
    else if (un < 14804){
      int j = (int)(un - 9804) * 4;
      int k = j / 400, c = j % 400;
      const float* s = &lsW[k*450 + c];
      float4 v = {s[0], s[1], s[2], s[3]};
      *(float4*)&lsW4[j] = v;
    }
    else if (un < 62804){
      int j = (int)(un - 14804) * 4;
      int m = j / 320, r = j % 320;
      int t = m / 50, k = m % 50;
      ushort4 o = {0,0,0,0};
      if (r < 300) o = f4bf(*(const float4*)&qmu[((size_t)k*12 + t)*300 + r]);
      *(ushort4*)&albf[j] = o;
    }
    else if (un < 63204){
      int j = (int)(un - 62804) * 4;
      float4 a = *(const float4*)&bi0[j], b = *(const float4*)&bh0[j];
      float4 v = {a.x+b.x, a.y+b.y, a.z+b.z, a.w+b.w};
      *(float4*)&bsum0[j] = v;
    }
    else if (un < 63604){
      int j = (int)(un - 63204) * 4;
      float4 a = *(const float4*)&bi1[j], b = *(const float4*)&bh1[j];
      float4 v = {a.x+b.x, a.y+b.y, a.z+b.z, a.w+b.w};
      *(float4*)&bsum1[j] = v;
    }
    else if (un < 63629){
      int j = (int)(un - 63604) * 4;
      #pragma unroll
      for (int q = 0; q < 4; ++q){
        int jj = j + q;
        mlb[jj] = (jj < 50) ? mb[jj] : lb[jj-50];
      }
    }
    else if (un < 63929){
      int j = (int)(un - 63629) * 4;
      *(float4*)&rs[j] = z4;
    }
    else if (un < 563929){
      long long rel = un - 63929;
      int half = (int)(rel / 160000);
      int j = (int)(rel % 160000) * 4;
      int ub = j / 3200, rem = j % 3200;
      int r = rem / 8, c = rem % 8;
      int ul = c >> 2;
      int u = ub*2 + ul;
      const float* src = (half == 0) ? whh0 : (half == 1) ? whh1 : wih1;
      float* dst = (half == 0) ? w0P : (half == 1) ? w1P : wi1P;
      float4 v = { src[((size_t)(0*400 + u))*400 + r],
                   src[((size_t)(1*400 + u))*400 + r],
                   src[((size_t)(2*400 + u))*400 + r],
                   src[((size_t)(3*400 + u))*400 + r] };
      *(float4*)&dst[j] = v;
    }
    else if (un < 1239769){
      int j = (int)(un - 563929) * 4;
      int row = j / 7040, v = j % 7040;
      ushort4 o = {0,0,0,0};
      if (v < 7000) o = f4bf(*(const float4*)&nbows[(size_t)row*7000 + v]);
      *(ushort4*)&nbbf[j] = o;
    }
    else if (un < 1943769){
      int j = (int)(un - 1239769) * 4;
      int row = j / 7040, v = j % 7040;
      ushort4 o = {0,0,0,0};
      if (v < 7000) o = f4bf(*(const float4*)&qmap_w[(size_t)row*7000 + v]);
      *(ushort4*)&qwbf[j] = o;
    }
    else if (un < 2110169){
      int j = (int)(un - 1943769) * 4;
      int row = j / 416, r = j % 416;
      ushort4 o = {0,0,0,0};
      if (r < 400) o = f4bf(*(const float4*)&wih0[(size_t)row*400 + r]);
      *(ushort4*)&w0bf[j] = o;
    }
    else if (un < 2510169){
      int j = (int)(un - 2110169) * 4;
      int row = j / 320, r = j % 320;
      ushort4 o = {0,0,0,0};
      if (r < 300) o = f4bf(*(const float4*)&rho1w[(size_t)row*300 + r]);
      *(ushort4*)&r1bf[j] = o;
    }
    else if (un < 2670169){
      int j = (int)(un - 2510169) * 4;
      int row = j / 320, r = j % 320;
      ushort4 o = {0,0,0,0};
      if (r < 300) o = f4bf(*(const float4*)&rho2w[(size_t)row*300 + r]);
      *(ushort4*)&r2bf[j] = o;
    }
    else {
      int j = (int)(un - 2670169) * 4;
      int c = j % 400;
      *(float4*)&inpf[j] = *(const float4*)&qb[c];
    }
  }
}

// ---------------- MFMA bf16 GEMM (standalone: inp split-K, X0 w/ f32-A) -----
__global__ __launch_bounds__(256) void gemm_bf16(
    const unsigned short* __restrict__ A, int lda,
    const unsigned short* __restrict__ B, int ldb,
    float* __restrict__ Cf, float* __restrict__ Cacc, int ldc,
    int M, int N, int Kp, int kchunk,
    const float* __restrict__ bias, const float* __restrict__ Af32)
{
  __shared__ unsigned short As[64][40];
  __shared__ unsigned short Bs[64][40];
  const int tid = threadIdx.x;
  const int m0 = blockIdx.y * 64, n0 = blockIdx.x * 64;
  const int kbeg = blockIdx.z * kchunk;
  const int kend = min(Kp, kbeg + kchunk);
  const int wave = tid >> 6, lane = tid & 63;
  const int wm = (wave >> 1) * 32, wn = (wave & 1) * 32;
  const int ra = tid >> 2, ck = (tid & 3) << 3;
  const int fr = lane & 15, fo = (lane >> 4) << 3;

  auto loadA = [&](int rA, int c)->int4{
    if (Af32){
      int4 r = make_int4(0,0,0,0);
      if (rA < M && c < 400){
        float4 f0 = *(const float4*)&Af32[(size_t)rA*400 + c];
        float4 f1 = *(const float4*)&Af32[(size_t)rA*400 + c + 4];
        ushort4 u0 = f4bf(f0), u1 = f4bf(f1);
        r.x = (int)u0.x | ((int)u0.y << 16);
        r.y = (int)u0.z | ((int)u0.w << 16);
        r.z = (int)u1.x | ((int)u1.y << 16);
        r.w = (int)u1.z | ((int)u1.w << 16);
      }
      return r;
    }
    return (rA < M) ? *(const int4*)&A[(size_t)rA*lda + c] : make_int4(0,0,0,0);
  };

  f32x4 acc00 = {0.f,0.f,0.f,0.f}, acc01 = {0.f,0.f,0.f,0.f};
  f32x4 acc10 = {0.f,0.f,0.f,0.f}, acc11 = {0.f,0.f,0.f,0.f};
  int4 pa, pb;
  {
    int rA = m0 + ra, rB = n0 + ra;
    pa = loadA(rA, kbeg + ck);
    pb = (rB < N) ? *(const int4*)&B[(size_t)rB*ldb + kbeg + ck] : make_int4(0,0,0,0);
  }
  for (int k0 = kbeg; k0 < kend; k0 += 32){
    *(int4*)&As[ra][ck] = pa;
    *(int4*)&Bs[ra][ck] = pb;
    __syncthreads();
    if (k0 + 32 < kend){
      int rA = m0 + ra, rB = n0 + ra;
      pa = loadA(rA, k0 + 32 + ck);
      pb = (rB < N) ? *(const int4*)&B[(size_t)rB*ldb + k0 + 32 + ck] : make_int4(0,0,0,0);
    }
    short8v a0 = *(const short8v*)&As[wm      + fr][fo];
    short8v a1 = *(const short8v*)&As[wm + 16 + fr][fo];
    short8v b0 = *(const short8v*)&Bs[wn      + fr][fo];
    short8v b1 = *(const short8v*)&Bs[wn + 16 + fr][fo];
    acc00 = __builtin_amdgcn_mfma_f32_16x16x32_bf16(a0, b0, acc00, 0, 0, 0);
    acc01 = __builtin_amdgcn_mfma_f32_16x16x32_bf16(a0, b1, acc01, 0, 0, 0);
    acc10 = __builtin_amdgcn_mfma_f32_16x16x32_bf16(a1, b0, acc10, 0, 0, 0);
    acc11 = __builtin_amdgcn_mfma_f32_16x16x32_bf16(a1, b1, acc11, 0, 0, 0);
    __syncthreads();
  }
  const int rbase = (lane >> 4) << 2;
  auto epi = [&](f32x4 ac0, f32x4 ac1, int mi){
    #pragma unroll
    for (int reg = 0; reg < 4; ++reg){
      const int gr = m0 + wm + mi*16 + rbase + reg;
      {
        int gc = n0 + wn + fr;
        if (gr < M && gc < N){
          if (Cacc) atomicAdd(&Cacc[(size_t)gr*ldc + gc], ac0[reg]);
          else Cf[(size_t)gr*ldc + gc] = ac0[reg] + (bias ? bias[gc] : 0.f);
        }
      }
      {
        int gc = n0 + wn + 16 + fr;
        if (gr < M && gc < N){
          if (Cacc) atomicAdd(&Cacc[(size_t)gr*ldc + gc], ac1[reg]);
          else Cf[(size_t)gr*ldc + gc] = ac1[reg] + (bias ? bias[gc] : 0.f);
        }
      }
    }
  };
  epi(acc00, acc01, 0);
  epi(acc10, acc11, 1);
}

// ---------------- beta GEMM device fn (f32 out + bias + rowsum) ----------------
__device__ void gemm_beta_dev(
    const unsigned short* __restrict__ A, int lda,
    const unsigned short* __restrict__ B, int ldb,
    float* __restrict__ Cf, int ldc,
    int M, int N, int Kp,
    const float* __restrict__ bias, float* __restrict__ rowsum,
    int bx, int by, char* smem)
{
  typedef unsigned short us;
  us (*As)[40] = (us(*)[40])smem;
  us (*Bs)[40] = (us(*)[40])(smem + 5120);
  float* sexp  = (float*)(smem + 10240);
  const int tid = threadIdx.x;
  const int m0 = by * 64, n0 = bx * 64;
  const int wave = tid >> 6, lane = tid & 63;
  const int wm = (wave >> 1) * 32, wn = (wave & 1) * 32;
  const int ra = tid >> 2, ck = (tid & 3) << 3;
  const int fr = lane & 15, fo = (lane >> 4) << 3;
  if (tid < 64) sexp[tid] = 0.f;

  f32x4 acc00 = {0.f,0.f,0.f,0.f}, acc01 = {0.f,0.f,0.f,0.f};
  f32x4 acc10 = {0.f,0.f,0.f,0.f}, acc11 = {0.f,0.f,0.f,0.f};
  int4 pa, pb;
  {
    int rA = m0 + ra, rB = n0 + ra;
    pa = (rA < M) ? *(const int4*)&A[(size_t)rA*lda + ck] : make_int4(0,0,0,0);
    pb = (rB < N) ? *(const int4*)&B[(size_t)rB*ldb + ck] : make_int4(0,0,0,0);
  }
  for (int k0 = 0; k0 < Kp; k0 += 32){
    *(int4*)&As[ra][ck] = pa;
    *(int4*)&Bs[ra][ck] = pb;
    __syncthreads();
    if (k0 + 32 < Kp){
      int rA = m0 + ra, rB = n0 + ra;
      pa = (rA < M) ? *(const int4*)&A[(size_t)rA*lda + k0 + 32 + ck] : make_int4(0,0,0,0);
      pb = (rB < N) ? *(const int4*)&B[(size_t)rB*ldb + k0 + 32 + ck] : make_int4(0,0,0,0);
    }
    short8v a0 = *(const short8v*)&As[wm      + fr][fo];
    short8v a1 = *(const short8v*)&As[wm + 16 + fr][fo];
    short8v b0 = *(const short8v*)&Bs[wn      + fr][fo];
    short8v b1 = *(const short8v*)&Bs[wn + 16 + fr][fo];
    acc00 = __builtin_amdgcn_mfma_f32_16x16x32_bf16(a0, b0, acc00, 0, 0, 0);
    acc01 = __builtin_amdgcn_mfma_f32_16x16x32_bf16(a0, b1, acc01, 0, 0, 0);
    acc10 = __builtin_amdgcn_mfma_f32_16x16x32_bf16(a1, b0, acc10, 0, 0, 0);
    acc11 = __builtin_amdgcn_mfma_f32_16x16x32_bf16(a1, b1, acc11, 0, 0, 0);
    __syncthreads();
  }
  const int rbase = (lane >> 4) << 2;
  auto epi = [&](f32x4 ac0, f32x4 ac1, int mi){
    #pragma unroll
    for (int reg = 0; reg < 4; ++reg){
      const int lr = wm + mi*16 + rbase + reg;
      const int gr = m0 + lr;
      float ex = 0.f;
      {
        int gc = n0 + wn + fr;
        if (gr < M && gc < N){
          float val = ac0[reg] + bias[gc];
          Cf[(size_t)gr*ldc + gc] = val;
          ex += __expf(val);
        }
      }
      {
        int gc = n0 + wn + 16 + fr;
        if (gr < M && gc < N){
          float val = ac1[reg] + bias[gc];
          Cf[(size_t)gr*ldc + gc] = val;
          ex += __expf(val);
        }
      }
      ex += __shfl_xor(ex, 1); ex += __shfl_xor(ex, 2);
      ex += __shfl_xor(ex, 4); ex += __shfl_xor(ex, 8);
      if (fr == 0 && gr < M) atomicAdd(&sexp[lr], ex);
    }
  };
  epi(acc00, acc01, 0);
  epi(acc10, acc11, 1);
  __syncthreads();
  if (tid < 64 && m0 + tid < M) atomicAdd(&rowsum[m0 + tid], sexp[tid]);
}

// ---------------- mega: LSTM step (blocks<400) + beta GEMM ride-along --------
__global__ __launch_bounds__(256) void lstm_mega(
    const float* __restrict__ X0,    const float* __restrict__ w0P,
    const float* __restrict__ wi1P,  const float* __restrict__ w1P,
    const float* __restrict__ bsum1,
    float* __restrict__ hs0, float* __restrict__ hs1,
    float* __restrict__ cst0, float* __restrict__ cst1, int step,
    const unsigned short* __restrict__ albf,
    const unsigned short* __restrict__ r1bf,
    const unsigned short* __restrict__ r2bf,
    const float* __restrict__ rho1b, const float* __restrict__ rho2b,
    float* __restrict__ beta, float* __restrict__ rs)
{
  __shared__ __align__(16) char smem[42496];
  const int tid = threadIdx.x;

  if (blockIdx.x >= 400){
    int tile = blockIdx.x - 400;
    if (step == 0){
      int bx = tile % 79, by = tile / 79;
      gemm_beta_dev(albf, 320, r1bf, 320, beta, 7000,
                    600, 5000, 320, rho1b, rs, bx, by, smem);
    } else {
      int bx = tile % 32, by = tile / 32;
      gemm_beta_dev(albf, 320, r2bf, 320, beta + 5000, 7000,
                    600, 2000, 320, rho2b, rs + 600, bx, by, smem);
    }
    return;
  }

  ushort4* hqb = (ushort4*)smem;                         // 25600B
  float4*  wq4 = (float4*)(smem + 25600);                // 12800B
  float4 (*red4)[32][2] = (float4(*)[32][2])(smem + 38400); // 4096B
  const int rh = tid >> 6;
  const int b  = (tid & 63) >> 1;
  const int ul = tid & 1;
  const int rq0 = rh * 25;

  if (blockIdx.x < 200){
    const int t = step;
    if (t >= 12) return;
    const int ub = blockIdx.x;
    const int U0 = ub * 2;
    if (t > 0){
      for (int i = tid; i < 3200; i += 256){
        int bb = i & 31, rq = i >> 5;
        hqb[rq*32 + bb] = f4bf(*(const float4*)&hs0[((size_t)(bb*12 + (t-1)))*400 + rq*4]);
      }
      for (int i = tid; i < 800; i += 256)
        wq4[i] = *(const float4*)&w0P[(size_t)ub*3200 + i*4];
      __syncthreads();
      float4 acc = {0.f,0.f,0.f,0.f};
      #pragma unroll 5
      for (int rq = rq0; rq < rq0 + 25; ++rq){
        ushort4 h4 = hqb[rq*32 + b];
        float hr[4] = {bf2f(h4.x), bf2f(h4.y), bf2f(h4.z), bf2f(h4.w)};
        #pragma unroll
        for (int dr = 0; dr < 4; ++dr){
          float4 w4 = wq4[(rq*4 + dr)*2 + ul];
          acc.x = fmaf(hr[dr], w4.x, acc.x);
          acc.y = fmaf(hr[dr], w4.y, acc.y);
          acc.z = fmaf(hr[dr], w4.z, acc.z);
          acc.w = fmaf(hr[dr], w4.w, acc.w);
        }
      }
      red4[rh][b][ul] = acc;
    }
    __syncthreads();
    if (tid < 64){
      const int bb = tid >> 1, uu = U0 + (tid & 1);
      float4 a = {0.f,0.f,0.f,0.f};
      if (t > 0){
        #pragma unroll
        for (int w = 0; w < 4; ++w){
          float4 r = red4[w][bb][tid & 1];
          a.x += r.x; a.y += r.y; a.z += r.z; a.w += r.w;
        }
      }
      const size_t xrow = ((size_t)bb*12 + t)*1600;
      float gi = a.x + X0[xrow          + uu];
      float gf = a.y + X0[xrow +  400   + uu];
      float gg = a.z + X0[xrow +  800   + uu];
      float go = a.w + X0[xrow + 1200   + uu];
      float ii = 1.f/(1.f + expf(-gi));
      float ff = 1.f/(1.f + expf(-gf));
      float tg = tanhf(gg);
      float oo = 1.f/(1.f + expf(-go));
      float c = (t == 0) ? 0.f : cst0[bb*400 + uu];
      c = ff*c + ii*tg;
      cst0[bb*400 + uu] = c;
      hs0[((size_t)bb*12 + t)*400 + uu] = oo * tanhf(c);
    }
  } else {
    const int t = step - 1;
    if (t < 0) return;
    const int ub = blockIdx.x - 200;
    const int U0 = ub * 2;
    float4 acc = {0.f,0.f,0.f,0.f};
    for (int i = tid; i < 3200; i += 256){
      int bb = i & 31, rq = i >> 5;
      hqb[rq*32 + bb] = f4bf(*(const float4*)&hs0[((size_t)(bb*12 + t))*400 + rq*4]);
    }
    for (int i = tid; i < 800; i += 256)
      wq4[i] = *(const float4*)&wi1P[(size_t)ub*3200 + i*4];
    __syncthreads();
    {
      #pragma unroll 5
      for (int rq = rq0; rq < rq0 + 25; ++rq){
        ushort4 h4 = hqb[rq*32 + b];
        float hr[4] = {bf2f(h4.x), bf2f(h4.y), bf2f(h4.z), bf2f(h4.w)};
        #pragma unroll
        for (int dr = 0; dr < 4; ++dr){
          float4 w4 = wq4[(rq*4 + dr)*2 + ul];
          acc.x = fmaf(hr[dr], w4.x, acc.x);
          acc.y = fmaf(hr[dr], w4.y, acc.y);
          acc.z = fmaf(hr[dr], w4.z, acc.z);
          acc.w = fmaf(hr[dr], w4.w, acc.w);
        }
      }
    }
    __syncthreads();
    if (t > 0){
      for (int i = tid; i < 3200; i += 256){
        int bb = i & 31, rq = i >> 5;
        hqb[rq*32 + bb] = f4bf(*(const float4*)&hs1[((size_t)(bb*12 + (t-1)))*400 + rq*4]);
      }
      for (int i = tid; i < 800; i += 256)
        wq4[i] = *(const float4*)&w1P[(size_t)ub*3200 + i*4];
    }
    __syncthreads();
    if (t > 0){
      #pragma unroll 5
      for (int rq = rq0; rq < rq0 + 25; ++rq){
        ushort4 h4 = hqb[rq*32 + b];
        float hr[4] = {bf2f(h4.x), bf2f(h4.y), bf2f(h4.z), bf2f(h4.w)};
        #pragma unroll
        for (int dr = 0; dr < 4; ++dr){
          float4 w4 = wq4[(rq*4 + dr)*2 + ul];
          acc.x = fmaf(hr[dr], w4.x, acc.x);
          acc.y = fmaf(hr[dr], w4.y, acc.y);
          acc.z = fmaf(hr[dr], w4.z, acc.z);
          acc.w = fmaf(hr[dr], w4.w, acc.w);
        }
      }
    }
    red4[rh][b][ul] = acc;
    __syncthreads();
    if (tid < 64){
      const int bb = tid >> 1, uu = U0 + (tid & 1);
      float4 a = {0.f,0.f,0.f,0.f};
      #pragma unroll
      for (int w = 0; w < 4; ++w){
        float4 r = red4[w][bb][tid & 1];
        a.x += r.x; a.y += r.y; a.z += r.z; a.w += r.w;
      }
      float gi = a.x + bsum1[        uu];
      float gf = a.y + bsum1[ 400 + uu];
      float gg = a.z + bsum1[ 800 + uu];
      float go = a.w + bsum1[1200 + uu];
      float ii = 1.f/(1.f + expf(-gi));
      float ff = 1.f/(1.f + expf(-gf));
      float tg = tanhf(gg);
      float oo = 1.f/(1.f + expf(-go));
      float c = (t == 0) ? 0.f : cst1[bb*400 + uu];
      c = ff*c + ii*tg;
      cst1[bb*400 + uu] = c;
      hs1[((size_t)bb*12 + t)*400 + uu] = oo * tanhf(c);
    }
  }
}

// ---------------- theta head w/ fused muH2 GEMM: one block per b ----------------
__global__ __launch_bounds__(256) void theta_par(
    const float* __restrict__ hs1,
    const float* __restrict__ mlsW,   // [100][400] (muW4|lsW4 contiguous)
    const float* __restrict__ mlb,    // [100]
    const float* __restrict__ muW, const float* __restrict__ lsW,
    float* __restrict__ theta, float* __restrict__ accs)
{
  __shared__ float h_s[12][400];
  __shared__ float mh[12][100];
  __shared__ float wm[50][51], wl[50][51];
  __shared__ float zs[12][50];
  const int tid = threadIdx.x;
  const int b = blockIdx.x;
  for (int i = tid; i < 1200; i += 256){
    int t = i / 100, rq = i % 100;
    *(float4*)&h_s[t][rq*4] = *(const float4*)&hs1[((size_t)(b*12 + t))*400 + rq*4];
  }
  for (int i = tid; i < 2500; i += 256){
    int k = i / 50, j = i % 50;
    wm[k][j] = muW[k*450 + 400 + j];
    wl[k][j] = lsW[k*450 + 400 + j];
  }
  __syncthreads();
  if (tid < 100){
    float acc[12];
    #pragma unroll
    for (int t = 0; t < 12; ++t) acc[t] = mlb[tid];
    for (int r = 0; r < 400; ++r){
      float w = mlsW[(size_t)tid*400 + r];
      #pragma unroll
      for (int t = 0; t < 12; ++t) acc[t] = fmaf(h_s[t][r], w, acc[t]);
    }
    #pragma unroll
    for (int t = 0; t < 12; ++t) mh[t][tid] = acc[t];
  }
  __syncthreads();
  const float dd = expf(LOG_DELTA) + 1e-6f;
  float kacc = 0.f;
  for (int t = 0; t < 12; ++t){
    float kpart = 0.f;
    if (tid < 50){
      int k = tid;
      float m = mh[t][k];
      float l = mh[t][50 + k];
      float zp = 0.f;
      if (t > 0){
        zp = zs[t-1][k];
        float sm = 0.f, sl = 0.f;
        #pragma unroll 5
        for (int j = 0; j < 50; ++j){
          float z = zs[t-1][j];
          sm = fmaf(z, wm[k][j], sm);
          sl = fmaf(z, wl[k][j], sl);
        }
        m += sm; l += sl;
      }
      zs[t][k] = m;
      float denom = (t > 0) ? dd : (1.f + 1e-6f);
      float pls = (t > 0) ? LOG_DELTA : 0.f;
      float d = m - zp;
      kpart = (expf(l) + d*d)/denom - 1.f + pls - l;
    }
    kpart = wsum64(kpart);
    if (tid == 0) kacc += 0.5f * kpart / 32.f;
    __syncthreads();
  }
  if (tid < 12){
    int t = tid;
    float m = -3.0e38f;
    for (int k = 0; k < 50; ++k) m = fmaxf(m, zs[t][k]);
    float S = 0.f;
    for (int k = 0; k < 50; ++k) S += expf(zs[t][k] - m);
    float inv = 1.f/S;
    for (int k = 0; k < 50; ++k)
      theta[((size_t)t*32 + b)*50 + k] = expf(zs[t][k] - m) * inv;
  }
  if (tid == 0) atomicAdd(&accs[6], kacc);
}

// ---------------- pass1 v9: bf16 bzg output ----------------
__global__ __launch_bounds__(256) void pass1(
    const float* __restrict__ blog, const float* __restrict__ rs,
    const float* __restrict__ theta,
    unsigned short* __restrict__ bzg,
    unsigned int* __restrict__ c1u,
    float* __restrict__ accs)
{
  const int t = blockIdx.y;
  const int v0 = blockIdx.x * 64;
  __shared__ float th[32][50];
  __shared__ __align__(16) float be[50][64];
  __shared__ unsigned int c0p[64][13];
  __shared__ unsigned int c1p[2][32][25];
  __shared__ float rlog[2][50];
  __shared__ float kred[4];
  const int tid = threadIdx.x;

  if (tid < 100){
    int p = tid / 50, k = tid % 50;
    rlog[p][k] = __logf(rs[p*600 + t*50 + k]);
  }
  float lg[13];
  #pragma unroll
  for (int j = 0; j < 13; ++j){
    int i = tid + j*256;
    lg[j] = -40.f;
    if (i < 3200){
      int k = i >> 6, vl = i & 63, v = v0 + vl;
      if (v < 7000) lg[j] = blog[((size_t)t*50 + k)*7000 + v];
    }
  }
  #pragma unroll
  for (int j = 0; j < 7; ++j){
    int i = tid + j*256;
    if (i < 1600) th[i/50][i%50] = theta[(size_t)t*1600 + i];
  }
  for (int i = tid; i < 832; i += 256) ((unsigned int*)c0p)[i] = 0u;
  #pragma unroll
  for (int j = 0; j < 7; ++j){
    int i = tid + j*256;
    if (i < 1600) ((unsigned int*)c1p)[i] = 0u;
  }
  if (tid < 4) kred[tid] = 0.f;
  __syncthreads();
  #pragma unroll
  for (int j = 0; j < 13; ++j){
    int i = tid + j*256;
    if (i < 3200){
      int k = i >> 6, vl = i & 63, v = v0 + vl;
      int p = (v >= 5000);
      be[k][vl] = __expf(lg[j] - rlog[p][k]);
    }
  }
  __syncthreads();

  const int b = tid >> 3, sub = tid & 7;
  int off[8];
  #pragma unroll
  for (int i = 0; i < 8; ++i) off[i] = ((i >> 2) ? 32 : 0) + sub*4 + (i & 3);

  float sx[8], mx[8];
  #pragma unroll
  for (int i = 0; i < 8; ++i){ sx[i] = 0.f; mx[i] = 0.f; }
  for (int k = 0; k < 50; ++k){
    float tk = th[b][k];
    float4 q0 = *(const float4*)&be[k][sub*4];
    float4 q1 = *(const float4*)&be[k][32 + sub*4];
    float bv[8] = {q0.x,q0.y,q0.z,q0.w,q1.x,q1.y,q1.z,q1.w};
    #pragma unroll
    for (int i = 0; i < 8; ++i){
      float x = tk * bv[i];
      sx[i] += x;
      mx[i] = fmaxf(mx[i], x);
    }
  }
  float inv[8], lS1[8], bnd[8];
  #pragma unroll
  for (int i = 0; i < 8; ++i){
    inv[i] = 1.f / (50.f + sx[i]);
    lS1[i] = LOG50 + sx[i] * 0.02f;
    bnd[i] = (1.f + mx[i]) * inv[i];
  }

  int ks[8]; float xs[8];
  unsigned fmask = 0;
  const int sbase = (t*32 + b)*7000 + v0;
  #pragma unroll
  for (int i = 0; i < 8; ++i){
    ks[i] = 0; xs[i] = 0.f;
    if (v0 + off[i] >= 7000) fmask |= 1u << i;
  }
  int round = 0;
  while (true){
    const unsigned roff = (unsigned)round * 0x9E3779B9u;
    #pragma unroll
    for (int i = 0; i < 8; ++i){
      if (!((fmask >> i) & 1u)){
        const unsigned bse = (unsigned)(sbase + off[i]) * 2u;
        float u1 = u01(bse + roff);
        float u2 = u01(bse + 1u + roff);
        int kp = min((int)(u1 * 50.f), 49);
        float x  = th[b][kp] * be[kp][off[i]];
        float pi = (1.f + x) * inv[i];
        float y  = pi - bnd[i];
        float ap = 1.f + y + 0.5f*y*y;
        if (u2 <= ap || round >= 7){
          ks[i] = kp; xs[i] = x; fmask |= 1u << i;
        }
      }
    }
    ++round;
    if (__all(fmask == 255u)) break;
  }

  float kA1 = 0.f, kB1 = 0.f, kA2 = 0.f, kB2 = 0.f;
  #pragma unroll
  for (int i = 0; i < 8; ++i){
    const int vl = off[i], v = v0 + vl;
    if (v < 7000){
      float pis  = (1.f + xs[i]) * inv[i];
      float lpis = xs[i] - lS1[i];
      float lt   = __logf(th[b][ks[i]]);
      if (v >= 5000){ kA2 += lt; kB2 += pis*lpis; }
      else          { kA1 += lt; kB1 += pis*lpis; }
      atomicAdd(&c0p[vl][ks[i] >> 2], 1u << (8*(ks[i] & 3)));
      atomicAdd(&c1p[(v >= 5000) ? 1 : 0][b][ks[i] >> 1],
                (ks[i] & 1) ? 65536u : 1u);
    }
  }
  kA1 = wsum64(kA1); kB1 = wsum64(kB1); kA2 = wsum64(kA2); kB2 = wsum64(kB2);
  if ((tid & 63) == 0){
    atomicAdd(&kred[0], kA1); atomicAdd(&kred[1], kB1);
    atomicAdd(&kred[2], kA2); atomicAdd(&kred[3], kB2);
  }
  __syncthreads();
  #pragma unroll
  for (int j = 0; j < 13; ++j){
    int i = tid + j*256;
    if (i < 3200){
      int k = i >> 6, vl = i & 63, v = v0 + vl;
      if (v < 7000){
        float cnt = (float)((c0p[vl][k >> 2] >> (8*(k & 3))) & 0xFFu);
        bzg[(size_t)t*350000 + (size_t)k*7000 + v] = f2bf(be[k][vl] * cnt * (1.f/32.f));
      }
    }
  }
  for (int i = tid; i < 1600; i += 256){
    int b2 = i / 50, k2 = i % 50;
    unsigned w1 = c1p[0][b2][k2 >> 1];
    unsigned w2 = c1p[1][b2][k2 >> 1];
    unsigned cnt1 = (k2 & 1) ? (w1 >> 16) : (w1 & 0xFFFFu);
    unsigned cnt2 = (k2 & 1) ? (w2 >> 16) : (w2 & 0xFFFFu);
    unsigned comb = cnt1 | (cnt2 << 16);
    if (comb) atomicAdd(&c1u[(size_t)t*1600 + i], comb);
  }
  if (tid < 4) atomicAdd(&accs[tid], kred[tid]);
}

// ---------------- pass2: log-likelihood (bf16 bzg) ----------------
__global__ __launch_bounds__(256) void pass2(
    const unsigned short* __restrict__ bzg, const float* __restrict__ theta,
    const unsigned int* __restrict__ c1u,
    const float* __restrict__ bows, float* __restrict__ accs)
{
  const int t = blockIdx.y, v0 = blockIdx.x * 64;
  __shared__ float tz[2][32][50];
  __shared__ __align__(16) float bzs[50][64];
  __shared__ float sr[2];
  const int tid = threadIdx.x;
  if (tid < 2) sr[tid] = 0.f;
  for (int i = tid; i < 1600; i += 256){
    int b = i / 50, k = i % 50;
    float th_ = theta[(size_t)t*1600 + i];
    unsigned cw = c1u[(size_t)t*1600 + i];
    tz[0][b][k] = th_ * (float)(cw & 0xFFFFu) * (1.f/5000.f);
    tz[1][b][k] = th_ * (float)(cw >> 16)     * (1.f/2000.f);
  }
  for (int i = tid; i < 3200; i += 256){
    int k = i >> 6, vl = i & 63, v = v0 + vl;
    bzs[k][vl] = (v < 7000) ? bf2f(bzg[(size_t)t*350000 + (size_t)k*7000 + v]) : 0.f;
  }
  __syncthreads();

  const int b = tid >> 3, sub = tid & 7;
  int off[8];
  #pragma unroll
  for (int i = 0; i < 8; ++i) off[i] = ((i >> 2) ? 32 : 0) + sub*4 + (i & 3);
  int part[8];
  #pragma unroll
  for (int i = 0; i < 8; ++i) part[i] = (v0 + off[i] >= 5000);
  float dot[8];
  #pragma unroll
  for (int i = 0; i < 8; ++i) dot[i] = 0.f;
  for (int k = 0; k < 50; ++k){
    float t0 = tz[0][b][k], t1 = tz[1][b][k];
    float4 q0 = *(const float4*)&bzs[k][sub*4];
    float4 q1 = *(const float4*)&bzs[k][32 + sub*4];
    float bv[8] = {q0.x,q0.y,q0.z,q0.w,q1.x,q1.y,q1.z,q1.w};
    #pragma unroll
    for (int i = 0; i < 8; ++i)
      dot[i] = fmaf(part[i] ? t1 : t0, bv[i], dot[i]);
  }
  float w8[8];
  const size_t brow = ((size_t)b*12 + t)*7000;
  if (v0 + 63 < 7000){
    float4 wa = *(const float4*)&bows[brow + v0 + sub*4];
    float4 wb = *(const float4*)&bows[brow + v0 + 32 + sub*4];
    w8[0]=wa.x; w8[1]=wa.y; w8[2]=wa.z; w8[3]=wa.w;
    w8[4]=wb.x; w8[5]=wb.y; w8[6]=wb.z; w8[7]=wb.w;
  } else {
    #pragma unroll
    for (int i = 0; i < 8; ++i)
      w8[i] = (v0 + off[i] < 7000) ? bows[brow + v0 + off[i]] : 0.f;
  }
  float s1 = 0.f, s2 = 0.f;
  #pragma unroll
  for (int i = 0; i < 8; ++i){
    const int v = v0 + off[i];
    if (v < 7000){
      const float l = __logf(dot[i]) * w8[i];
      if (part[i]) s2 += l; else s1 += l;
    }
  }
  s1 = wsum64(s1); s2 = wsum64(s2);
  if ((tid & 63) == 0){ atomicAdd(&sr[0], s1); atomicAdd(&sr[1], s2); }
  __syncthreads();
  if (tid < 2) atomicAdd(&accs[4 + tid], sr[tid]);
}

// ---------------- finalize (sums kld partials too) ----------------
__global__ void finalize_k(const float* __restrict__ accs,
                           const float* __restrict__ kldp,
                           float* __restrict__ out){
  const int tid = threadIdx.x;
  float s = 0.f;
  for (int i = tid; i < 600; i += 64) s += kldp[i];
  s = wsum64(s);
  if (tid == 0){
    out[0] = -(accs[4] + accs[5]) * (1.f/32.f);
    out[1] = accs[6];
    out[2] = -accs[0]/(32.f*5000.f) - accs[1]/32.f;
    out[3] = -accs[2]/(32.f*2000.f) - accs[3]/32.f;
    out[4] = s;
  }
}

// ---------------- host launcher ----------------
extern "C" void kernel_launch(void* const* d_in, const int* in_sizes, int n_in,
                              void* d_out, int out_size, void* d_ws, size_t ws_size,
                              hipStream_t stream)
{
  const float* bows   = (const float*)d_in[0];
  const float* nbows  = (const float*)d_in[1];
  const float* qmap_w = (const float*)d_in[2];
  const float* qmap_b = (const float*)d_in[3];
  const float* wih0   = (const float*)d_in[4];
  const float* whh0   = (const float*)d_in[5];
  const float* bih0   = (const float*)d_in[6];
  const float* bhh0   = (const float*)d_in[7];
  const float* wih1   = (const float*)d_in[8];
  const float* whh1   = (const float*)d_in[9];
  const float* bih1   = (const float*)d_in[10];
  const float* bhh1   = (const float*)d_in[11];
  const float* muW    = (const float*)d_in[12];
  const float* muB    = (const float*)d_in[13];
  const float* lsW    = (const float*)d_in[14];
  const float* lsB    = (const float*)d_in[15];
  const float* qmu    = (const float*)d_in[16];
  const float* qlsa   = (const float*)d_in[17];
  const float* rho1w  = (const float*)d_in[18];
  const float* rho1b  = (const float*)d_in[19];
  const float* rho2w  = (const float*)d_in[20];
  const float* rho2b  = (const float*)d_in[21];

  float* ws  = (float*)d_ws;
  float* out = (float*)d_out;

  unsigned int* c1u = (unsigned int*)(ws + OFF_C1G1);
  float* kldp  = ws + OFF_KLDP;
  float* accs  = ws + OFF_ACCS;
  unsigned short* bzg = (unsigned short*)(ws + OFF_C0G);
  float* beta  = ws + OFF_BETA;
  float* inpf  = ws + OFF_ALPHAT;
  float* X0    = ws + OFF_X0;
  float* hs0   = ws + OFF_OUT0;
  float* hs1   = ws + OFF_OUT1;
  float* cst0  = ws + OFF_CST;
  float* cst1  = ws + OFF_CST1;
  float* theta = ws + OFF_THETA;
  float* muW4  = ws + OFF_MUW4;
  float* bsum0 = ws + OFF_LTH;
  float* bsum1 = ws + OFF_LTH + 1600;
  float* mlb   = ws + OFF_LTH + 3200;
  float* rs    = ws + OFF_RS;
  unsigned short* nbbf  = (unsigned short*)(ws + OFF_NBBF);
  unsigned short* qwbf  = (unsigned short*)(ws + OFF_QWBF);
  unsigned short* w0bf  = (unsigned short*)(ws + OFF_W0BF);
  unsigned short* albf  = (unsigned short*)(ws + OFF_ALBF);
  unsigned short* r1bf  = (unsigned short*)(ws + OFF_R1BF);
  unsigned short* r2bf  = (unsigned short*)(ws + OFF_R2BF);
  float* w0P  = ws + OFF_W0P;
  float* w1P  = ws + OFF_W1P;
  float* wi1P = ws + OFF_WI1P;

  // prep (blocks 0..2047) + kld_alpha (blocks 2048..2647)
  prep_misc<<<2648, 256, 0, stream>>>(ws, muW, lsW, qmu, qlsa, bih0, bhh0,
                                      bih1, bhh1, muB, lsB, qmap_b,
                                      whh0, whh1, wih1,
                                      nbows, qmap_w, wih0, rho1w, rho2w);

  // inp_f32 += nbows_bf @ qmap_w_bf^T  (split-K x10; bias pre-init'd in prep)
  gemm_bf16<<<dim3(7,6,10), 256, 0, stream>>>(nbbf, 7040, qwbf, 7040,
                                              nullptr, inpf, 400,
                                              384, 400, 7040, 704,
                                              nullptr, nullptr);
  // X0 = bf16(inp_f32) @ wih0^T + (bih0+bhh0)   (f32-A conversion fused)
  gemm_bf16<<<dim3(25,6,1), 256, 0, stream>>>(nullptr, 0, w0bf, 416,
                                              X0, nullptr, 1600,
                                              384, 1600, 416, 416,
                                              bsum0, inpf);
  // pipelined double-layer LSTM: 13 launches; beta GEMMs ride along steps 0/1
  for (int i = 0; i < 13; ++i){
    int grid = (i == 0) ? 1190 : (i == 1) ? 720 : 400;
    lstm_mega<<<grid, 256, 0, stream>>>(X0, w0P, wi1P, w1P, bsum1,
                                        hs0, hs1, cst0, cst1, i,
                                        albf, r1bf, r2bf, rho1b, rho2b,
                                        beta, rs);
  }

  // theta head with fused muH2 GEMM
  theta_par<<<32, 256, 0, stream>>>(hs1, muW4, mlb, muW, lsW, theta, accs);

  pass1<<<dim3(110,12), 256, 0, stream>>>(beta, rs, theta, bzg, c1u, accs);
  pass2<<<dim3(110,12), 256, 0, stream>>>(bzg, theta, c1u, bows, accs);

  finalize_k<<<1, 64, 0, stream>>>(accs, kldp, out);
}